// Round 3
// baseline (319.934 us; speedup 1.0000x reference)
//
#include <hip/hip_runtime.h>
#include <hip/hip_fp16.h>

#define N_PTS 100000
#define KSZ 9
#define C_IN 24
#define C_HID 144
#define C_OUT 24
#define G4_HID 36   // C_HID/4
#define G8_HID 18   // C_HID/8
#define G4_OUT 6    // C_OUT/4
#define EPSV 1e-5f

// ---- workspace layout ----
// bytes: x1h (fp16, (N+1)*144) | x2h (fp16, N*144) | y3 (f32, N*24) | stats (f32)
#define X1H_B     0
#define X2H_B     28800288                    // (100001*144*2), 16B aligned
#define Y3F_O     14400072                    // float index of y3 (byte 57600288)
#define ST_O      16800072                    // float index of stats (byte 67200288)
#define MU1_O     (ST_O + 0)
#define M1_O      (ST_O + 32)
#define SC1_O     (ST_O + 640)
#define SH1_O     (ST_O + 800)
#define SUM2_O    (ST_O + 960)
#define SQ2_O     (ST_O + 1120)
#define SC2_O     (ST_O + 1280)
#define SH2_O     (ST_O + 1440)
#define SUM3_O    (ST_O + 1600)
#define SQ3_O     (ST_O + 1632)
#define SC3_O     (ST_O + 1664)
#define SH3_O     (ST_O + 1696)
#define ST_SIZE   1728

__device__ inline float4 f4z() { return make_float4(0.f, 0.f, 0.f, 0.f); }
__device__ inline float4 f4_add(float4 a, float4 b) {
    return make_float4(a.x + b.x, a.y + b.y, a.z + b.z, a.w + b.w);
}
__device__ inline float4 f4_fma4(float4 a, float4 b, float4 c) {
    return make_float4(fmaf(a.x, b.x, c.x), fmaf(a.y, b.y, c.y),
                       fmaf(a.z, b.z, c.z), fmaf(a.w, b.w, c.w));
}
__device__ inline float4 f4_fma_s(float s, float4 b, float4 c) {
    return make_float4(fmaf(s, b.x, c.x), fmaf(s, b.y, c.y),
                       fmaf(s, b.z, c.z), fmaf(s, b.w, c.w));
}
__device__ inline float4 f4_clamp6(float4 a) {
    return make_float4(fminf(fmaxf(a.x, 0.f), 6.f), fminf(fmaxf(a.y, 0.f), 6.f),
                       fminf(fmaxf(a.z, 0.f), 6.f), fminf(fmaxf(a.w, 0.f), 6.f));
}
__device__ inline unsigned pack2(float a, float b) {
    __half2 h = __floats2half2_rn(a, b);
    return *reinterpret_cast<unsigned*>(&h);
}
__device__ inline float2 uph(unsigned u) {
    __half2 h = *reinterpret_cast<__half2*>(&u);
    return __half22float2(h);
}

// ---- K0: zero stats + fp16 sentinel row
__global__ __launch_bounds__(256) void k_init(float* ws) {
    int t = threadIdx.x;
    for (int i = t; i < ST_SIZE; i += 256) ws[ST_O + i] = 0.f;
    if (t < G8_HID) {
        uint4 z; z.x = 0u; z.y = 0u; z.z = 0u; z.w = 0u;
        ((uint4*)ws)[(size_t)N_PTS * G8_HID + t] = z;
    }
}

// ---- K1: feats moments: mu1[24] = sum(F), M1[24x24] = F^T F (raw sums)
#define MROWS 128
__device__ inline float task_acc(const float* tile, int cnt, int task) {
    if (task < 576) {
        int i = task / 24, j = task % 24;
        float a = 0.f;
        for (int r = 0; r < cnt; r++) a += tile[r * 24 + i] * tile[r * 24 + j];
        return a;
    }
    int k = task - 576;
    float a = 0.f;
    for (int r = 0; r < cnt; r++) a += tile[r * 24 + k];
    return a;
}
__global__ __launch_bounds__(256) void k_moments(const float* __restrict__ feats,
                                                 float* __restrict__ ws) {
    __shared__ float tile[MROWS * C_IN];
    int t = threadIdx.x;
    float acc0 = 0.f, acc1 = 0.f, acc2 = 0.f;
    int nChunks = (N_PTS + MROWS - 1) / MROWS;
    for (int ch = blockIdx.x; ch < nChunks; ch += gridDim.x) {
        int r0 = ch * MROWS;
        int cnt = min(MROWS, N_PTS - r0);
        __syncthreads();
        for (int e = t; e < cnt * C_IN; e += 256) tile[e] = feats[(size_t)r0 * C_IN + e];
        __syncthreads();
        acc0 += task_acc(tile, cnt, t);
        acc1 += task_acc(tile, cnt, t + 256);
        if (t < 88) acc2 += task_acc(tile, cnt, t + 512);
    }
    atomicAdd(&ws[M1_O + t], acc0);
    atomicAdd(&ws[M1_O + t + 256], acc1);
    if (t < 88) {
        int task = t + 512;
        if (task < 576) atomicAdd(&ws[M1_O + task], acc2);
        else            atomicAdd(&ws[MU1_O + task - 576], acc2);
    }
}

// ---- K2: BN1 closed form
__global__ void k_fin1(const float* __restrict__ w1, const float* __restrict__ g1,
                       const float* __restrict__ b1, float* __restrict__ ws) {
    int c = threadIdx.x;
    if (c >= C_HID) return;
    float wc[C_IN];
    for (int k = 0; k < C_IN; k++) wc[k] = w1[k * C_HID + c];
    const float invN = 1.f / (float)N_PTS;
    float mean = 0.f;
    for (int k = 0; k < C_IN; k++) mean += ws[MU1_O + k] * wc[k];
    mean *= invN;
    float e2 = 0.f;
    for (int i = 0; i < C_IN; i++) {
        float s = 0.f;
        for (int j = 0; j < C_IN; j++) s += ws[M1_O + i * 24 + j] * wc[j];
        e2 += wc[i] * s;
    }
    e2 *= invN;
    float var = e2 - mean * mean;
    float s1 = g1[c] * rsqrtf(var + EPSV);
    ws[SC1_O + c] = s1;
    ws[SH1_O + c] = b1[c] - mean * s1;
}

// ---- K3: GEMM1 fused BN1+relu6 -> x1h (fp16), 8 channels/thread
__global__ __launch_bounds__(256) void k_gemm1(const float* __restrict__ feats,
                                               const float* __restrict__ w1,
                                               float* __restrict__ ws) {
    __shared__ float4 w1s[C_IN * G4_HID];
    __shared__ float4 sc[G4_HID], sh[G4_HID];
    int t = threadIdx.x;
    for (int e = t; e < C_IN * G4_HID; e += 256) w1s[e] = ((const float4*)w1)[e];
    if (t < G4_HID) {
        sc[t] = ((const float4*)(ws + SC1_O))[t];
        sh[t] = ((const float4*)(ws + SH1_O))[t];
    }
    __syncthreads();
    uint4* x1u = (uint4*)ws;
    const int T = N_PTS * G8_HID;
    for (int tau = blockIdx.x * 256 + t; tau < T; tau += gridDim.x * 256) {
        int p = tau / G8_HID;
        int g = tau % G8_HID;
        const float4* fr = (const float4*)(feats + (size_t)p * C_IN);
        float4 a0 = f4z(), a1 = f4z();
#pragma unroll
        for (int q = 0; q < 6; q++) {
            float4 fq = fr[q];
            a0 = f4_fma_s(fq.x, w1s[(4 * q + 0) * G4_HID + 2 * g], a0);
            a1 = f4_fma_s(fq.x, w1s[(4 * q + 0) * G4_HID + 2 * g + 1], a1);
            a0 = f4_fma_s(fq.y, w1s[(4 * q + 1) * G4_HID + 2 * g], a0);
            a1 = f4_fma_s(fq.y, w1s[(4 * q + 1) * G4_HID + 2 * g + 1], a1);
            a0 = f4_fma_s(fq.z, w1s[(4 * q + 2) * G4_HID + 2 * g], a0);
            a1 = f4_fma_s(fq.z, w1s[(4 * q + 2) * G4_HID + 2 * g + 1], a1);
            a0 = f4_fma_s(fq.w, w1s[(4 * q + 3) * G4_HID + 2 * g], a0);
            a1 = f4_fma_s(fq.w, w1s[(4 * q + 3) * G4_HID + 2 * g + 1], a1);
        }
        a0 = f4_clamp6(f4_fma4(a0, sc[2 * g], sh[2 * g]));
        a1 = f4_clamp6(f4_fma4(a1, sc[2 * g + 1], sh[2 * g + 1]));
        uint4 o;
        o.x = pack2(a0.x, a0.y); o.y = pack2(a0.z, a0.w);
        o.z = pack2(a1.x, a1.y); o.w = pack2(a1.z, a1.w);
        x1u[tau] = o;
    }
}

// ---- K4: channelwise 3x3 conv (fp16 gather, 8ch/lane) + fused BN2 stats
__global__ __launch_bounds__(256) void k_conv(const float* __restrict__ w2,
                                              const int* __restrict__ in_idx,
                                              float* __restrict__ ws) {
    __shared__ float lsum[C_HID], lsq[C_HID];
    int t = threadIdx.x;
    if (t < C_HID) { lsum[t] = 0.f; lsq[t] = 0.f; }
    __syncthreads();
    const uint4* x1u = (const uint4*)ws;
    uint4* x2u = (uint4*)((char*)ws + X2H_B);
    bool active = t < 252;
    int pt = t / G8_HID, g = t % G8_HID;   // 14 points x 18 lane-groups
    const float4* w2v = (const float4*)w2;
    float4 wA[KSZ], wB[KSZ];
#pragma unroll
    for (int k = 0; k < KSZ; k++) {
        wA[k] = w2v[k * G4_HID + 2 * g];
        wB[k] = w2v[k * G4_HID + 2 * g + 1];
    }
    float4 rsA = f4z(), rsB = f4z(), rqA = f4z(), rqB = f4z();
    int nChunks = (N_PTS + 13) / 14;
    for (int ch = blockIdx.x; ch < nChunks; ch += gridDim.x) {
        int p = ch * 14 + pt;
        if (active && p < N_PTS) {
            int idx[KSZ];
#pragma unroll
            for (int k = 0; k < KSZ; k++) idx[k] = in_idx[k * N_PTS + p];
            float4 aA = f4z(), aB = f4z();
#pragma unroll
            for (int k = 0; k < KSZ; k++) {
                uint4 v = x1u[(size_t)idx[k] * G8_HID + g];  // idx==N -> zero sentinel
                float2 f0 = uph(v.x), f1 = uph(v.y), f2 = uph(v.z), f3 = uph(v.w);
                aA = f4_fma4(wA[k], make_float4(f0.x, f0.y, f1.x, f1.y), aA);
                aB = f4_fma4(wB[k], make_float4(f2.x, f2.y, f3.x, f3.y), aB);
            }
            uint4 o;
            o.x = pack2(aA.x, aA.y); o.y = pack2(aA.z, aA.w);
            o.z = pack2(aB.x, aB.y); o.w = pack2(aB.z, aB.w);
            x2u[(size_t)p * G8_HID + g] = o;
            rsA = f4_add(rsA, aA); rsB = f4_add(rsB, aB);
            rqA = f4_fma4(aA, aA, rqA); rqB = f4_fma4(aB, aB, rqB);
        }
    }
    if (active) {
        int c0 = 8 * g;
        atomicAdd(&lsum[c0 + 0], rsA.x); atomicAdd(&lsum[c0 + 1], rsA.y);
        atomicAdd(&lsum[c0 + 2], rsA.z); atomicAdd(&lsum[c0 + 3], rsA.w);
        atomicAdd(&lsum[c0 + 4], rsB.x); atomicAdd(&lsum[c0 + 5], rsB.y);
        atomicAdd(&lsum[c0 + 6], rsB.z); atomicAdd(&lsum[c0 + 7], rsB.w);
        atomicAdd(&lsq[c0 + 0], rqA.x);  atomicAdd(&lsq[c0 + 1], rqA.y);
        atomicAdd(&lsq[c0 + 2], rqA.z);  atomicAdd(&lsq[c0 + 3], rqA.w);
        atomicAdd(&lsq[c0 + 4], rqB.x);  atomicAdd(&lsq[c0 + 5], rqB.y);
        atomicAdd(&lsq[c0 + 6], rqB.z);  atomicAdd(&lsq[c0 + 7], rqB.w);
    }
    __syncthreads();
    if (t < C_HID) {
        atomicAdd(&ws[SUM2_O + t], lsum[t]);
        atomicAdd(&ws[SQ2_O + t], lsq[t]);
    }
}

// ---- K5: BN2 finalize
__global__ void k_fin2(const float* __restrict__ g2, const float* __restrict__ b2,
                       float* __restrict__ ws) {
    int c = threadIdx.x;
    if (c >= C_HID) return;
    const float invN = 1.f / (float)N_PTS;
    float mean = ws[SUM2_O + c] * invN;
    float var = ws[SQ2_O + c] * invN - mean * mean;
    float s = g2[c] * rsqrtf(var + EPSV);
    ws[SC2_O + c] = s;
    ws[SH2_O + c] = b2[c] - mean * s;
}

// ---- K6: GEMM2 (bn2+relu6 on the fly) -> y3, fused BN3 stats
#define TP 64
__global__ __launch_bounds__(256) void k_gemm2(const float* __restrict__ w3,
                                               float* __restrict__ ws) {
    __shared__ float xs[TP * 145];
    __shared__ float w3s[C_HID * C_OUT];
    __shared__ float sc2s[C_HID], sh2s[C_HID];
    __shared__ float ssum[C_OUT], ssq[C_OUT];
    int t = threadIdx.x;
    for (int e = t; e < C_HID * C_OUT / 4; e += 256)
        ((float4*)w3s)[e] = ((const float4*)w3)[e];
    if (t < C_HID) { sc2s[t] = ws[SC2_O + t]; sh2s[t] = ws[SH2_O + t]; }
    if (t < C_OUT) { ssum[t] = 0.f; ssq[t] = 0.f; }
    __syncthreads();   // <<< FIX: sc2s/sh2s must be visible before the staging loop reads them
    const uint4* x2u = (const uint4*)((char*)ws + X2H_B);
    int p0 = blockIdx.x * TP;
    // stage x2 tile with BN2+relu6 applied
    for (int e = t; e < TP * G8_HID; e += 256) {
        int row = e / G8_HID, col = e % G8_HID;
        int p = p0 + row;
        int c0 = 8 * col;
        float v[8];
        if (p < N_PTS) {
            uint4 u = x2u[(size_t)p * G8_HID + col];
            float2 f0 = uph(u.x), f1 = uph(u.y), f2 = uph(u.z), f3 = uph(u.w);
            v[0] = f0.x; v[1] = f0.y; v[2] = f1.x; v[3] = f1.y;
            v[4] = f2.x; v[5] = f2.y; v[6] = f3.x; v[7] = f3.y;
#pragma unroll
            for (int i = 0; i < 8; i++)
                v[i] = fminf(fmaxf(fmaf(v[i], sc2s[c0 + i], sh2s[c0 + i]), 0.f), 6.f);
        } else {
#pragma unroll
            for (int i = 0; i < 8; i++) v[i] = 0.f;
        }
#pragma unroll
        for (int i = 0; i < 8; i++) xs[row * 145 + c0 + i] = v[i];
    }
    __syncthreads();
    int pl = t & 63, cg = t >> 6;          // wave == channel group
    int c0 = 6 * cg;
    float acc[6] = {0.f, 0.f, 0.f, 0.f, 0.f, 0.f};
    const float* xr = xs + pl * 145;
#pragma unroll 4
    for (int h = 0; h < C_HID; h++) {
        float x = xr[h];
#pragma unroll
        for (int j = 0; j < 6; j++) acc[j] = fmaf(x, w3s[h * C_OUT + c0 + j], acc[j]);
    }
    int p = p0 + pl;
    bool valid = p < N_PTS;
    float* y3 = ws + Y3F_O;
    if (valid) {
#pragma unroll
        for (int j = 0; j < 6; j++) y3[(size_t)p * C_OUT + c0 + j] = acc[j];
    }
    float s[6], q[6];
#pragma unroll
    for (int j = 0; j < 6; j++) {
        s[j] = valid ? acc[j] : 0.f;
        q[j] = s[j] * s[j];
    }
#pragma unroll
    for (int off = 32; off > 0; off >>= 1) {
#pragma unroll
        for (int j = 0; j < 6; j++) {
            s[j] += __shfl_down(s[j], off);
            q[j] += __shfl_down(q[j], off);
        }
    }
    if (pl == 0) {
#pragma unroll
        for (int j = 0; j < 6; j++) {
            atomicAdd(&ssum[c0 + j], s[j]);
            atomicAdd(&ssq[c0 + j], q[j]);
        }
    }
    __syncthreads();
    if (t < C_OUT) {
        atomicAdd(&ws[SUM3_O + t], ssum[t]);
        atomicAdd(&ws[SQ3_O + t], ssq[t]);
    }
}

// ---- K8: BN3 finalize
__global__ void k_fin3(const float* __restrict__ g3, const float* __restrict__ b3,
                       float* __restrict__ ws) {
    int c = threadIdx.x;
    if (c >= C_OUT) return;
    const float invN = 1.f / (float)N_PTS;
    float mean = ws[SUM3_O + c] * invN;
    float var = ws[SQ3_O + c] * invN - mean * mean;
    float s = g3[c] * rsqrtf(var + EPSV);
    ws[SC3_O + c] = s;
    ws[SH3_O + c] = b3[c] - mean * s;
}

// ---- K9: out = bn3(y3) + feats
__global__ __launch_bounds__(256) void k_out(const float* __restrict__ feats,
                                             const float* __restrict__ ws,
                                             float* __restrict__ out) {
    int t4 = blockIdx.x * 256 + threadIdx.x;
    const int T = N_PTS * G4_OUT;
    if (t4 >= T) return;
    int g = t4 % G4_OUT;
    float4 y = ((const float4*)(ws + Y3F_O))[t4];
    float4 s = ((const float4*)(ws + SC3_O))[g];
    float4 b = ((const float4*)(ws + SH3_O))[g];
    float4 f = ((const float4*)feats)[t4];
    ((float4*)out)[t4] = f4_add(f4_fma4(y, s, b), f);
}

extern "C" void kernel_launch(void* const* d_in, const int* in_sizes, int n_in,
                              void* d_out, int out_size, void* d_ws, size_t ws_size,
                              hipStream_t stream) {
    const float* feats = (const float*)d_in[0];
    const float* w1 = (const float*)d_in[1];
    const float* g1 = (const float*)d_in[2];
    const float* b1 = (const float*)d_in[3];
    const float* w2 = (const float*)d_in[4];
    const float* g2 = (const float*)d_in[5];
    const float* b2 = (const float*)d_in[6];
    const float* w3 = (const float*)d_in[7];
    const float* g3 = (const float*)d_in[8];
    const float* b3 = (const float*)d_in[9];
    const int* in_idx = (const int*)d_in[10];
    float* ws = (float*)d_ws;
    float* out = (float*)d_out;

    hipLaunchKernelGGL(k_init, dim3(1), dim3(256), 0, stream, ws);
    hipLaunchKernelGGL(k_moments, dim3(256), dim3(256), 0, stream, feats, ws);
    hipLaunchKernelGGL(k_fin1, dim3(1), dim3(192), 0, stream, w1, g1, b1, ws);
    hipLaunchKernelGGL(k_gemm1, dim3(2048), dim3(256), 0, stream, feats, w1, ws);
    hipLaunchKernelGGL(k_conv, dim3(2048), dim3(256), 0, stream, w2, in_idx, ws);
    hipLaunchKernelGGL(k_fin2, dim3(1), dim3(192), 0, stream, g2, b2, ws);
    hipLaunchKernelGGL(k_gemm2, dim3((N_PTS + TP - 1) / TP), dim3(256), 0, stream, w3, ws);
    hipLaunchKernelGGL(k_fin3, dim3(1), dim3(64), 0, stream, g3, b3, ws);
    hipLaunchKernelGGL(k_out, dim3((N_PTS * G4_OUT + 255) / 256), dim3(256), 0, stream,
                       feats, ws, out);
}

// Round 4
// 312.915 us; speedup vs baseline: 1.0224x; 1.0224x over previous
//
#include <hip/hip_runtime.h>
#include <hip/hip_fp16.h>

#define N_PTS 100000
#define KSZ 9
#define C_IN 24
#define C_HID 144
#define C_OUT 24
#define G4_HID 36   // C_HID/4
#define G8_HID 18   // C_HID/8
#define G4_OUT 6    // C_OUT/4
#define EPSV 1e-5f

// ---- workspace layout ----
// x1h fp16 (N+1)*144 | x2h fp16 N*144 | y3 f32 N*24 | stats f32 (1024)
#define X2H_B     28800288                    // byte offset of x2h
#define SENT_B    28800000                    // byte offset of fp16 sentinel row (288 B)
#define Y3F_O     14400072                    // float index of y3
#define ST_O      16800072                    // float index of stats (byte 67200288)
#define ST_B      67200288
#define MU1_O     (ST_O + 0)      // 24
#define M1_O      (ST_O + 32)     // 576
#define SUM2_O    (ST_O + 640)    // 144
#define SQ2_O     (ST_O + 800)    // 144
#define SUM3_O    (ST_O + 960)    // 24
#define SQ3_O     (ST_O + 992)    // 24
// memset covers ST_O .. ST_O+1024 floats (4096 B)

__device__ inline float4 f4z() { return make_float4(0.f, 0.f, 0.f, 0.f); }
__device__ inline float4 f4_add(float4 a, float4 b) {
    return make_float4(a.x + b.x, a.y + b.y, a.z + b.z, a.w + b.w);
}
__device__ inline float4 f4_fma4(float4 a, float4 b, float4 c) {
    return make_float4(fmaf(a.x, b.x, c.x), fmaf(a.y, b.y, c.y),
                       fmaf(a.z, b.z, c.z), fmaf(a.w, b.w, c.w));
}
__device__ inline float4 f4_fma_s(float s, float4 b, float4 c) {
    return make_float4(fmaf(s, b.x, c.x), fmaf(s, b.y, c.y),
                       fmaf(s, b.z, c.z), fmaf(s, b.w, c.w));
}
__device__ inline float4 f4_clamp6(float4 a) {
    return make_float4(fminf(fmaxf(a.x, 0.f), 6.f), fminf(fmaxf(a.y, 0.f), 6.f),
                       fminf(fmaxf(a.z, 0.f), 6.f), fminf(fmaxf(a.w, 0.f), 6.f));
}
__device__ inline unsigned pack2(float a, float b) {
    __half2 h = __floats2half2_rn(a, b);
    return *reinterpret_cast<unsigned*>(&h);
}
__device__ inline float2 uph(unsigned u) {
    __half2 h = *reinterpret_cast<__half2*>(&u);
    return __half22float2(h);
}

// ---- K1: feats moments: MU1[24]=sum(F), M1[24x24]=F^T F (raw sums, atomics;
//      accumulators pre-zeroed by hipMemsetAsync)
#define MROWS 128
__device__ inline float task_acc(const float* tile, int cnt, int task) {
    if (task < 576) {
        int i = task / 24, j = task % 24;
        float a = 0.f;
        for (int r = 0; r < cnt; r++) a += tile[r * 24 + i] * tile[r * 24 + j];
        return a;
    }
    int k = task - 576;
    float a = 0.f;
    for (int r = 0; r < cnt; r++) a += tile[r * 24 + k];
    return a;
}
__global__ __launch_bounds__(256) void k_moments(const float* __restrict__ feats,
                                                 float* __restrict__ ws) {
    __shared__ float tile[MROWS * C_IN];
    int t = threadIdx.x;
    float acc0 = 0.f, acc1 = 0.f, acc2 = 0.f;
    int nChunks = (N_PTS + MROWS - 1) / MROWS;
    for (int ch = blockIdx.x; ch < nChunks; ch += gridDim.x) {
        int r0 = ch * MROWS;
        int cnt = min(MROWS, N_PTS - r0);
        __syncthreads();
        for (int e = t; e < cnt * C_IN; e += 256) tile[e] = feats[(size_t)r0 * C_IN + e];
        __syncthreads();
        acc0 += task_acc(tile, cnt, t);
        acc1 += task_acc(tile, cnt, t + 256);
        if (t < 88) acc2 += task_acc(tile, cnt, t + 512);
    }
    atomicAdd(&ws[M1_O + t], acc0);
    atomicAdd(&ws[M1_O + t + 256], acc1);
    if (t < 88) {
        int task = t + 512;
        if (task < 576) atomicAdd(&ws[M1_O + task], acc2);
        else            atomicAdd(&ws[MU1_O + task - 576], acc2);
    }
}

// ---- K2: GEMM1 with in-block BN1 closed-form finalize, fused BN1+relu6 -> x1h fp16
__global__ __launch_bounds__(256) void k_gemm1(const float* __restrict__ feats,
                                               const float* __restrict__ w1,
                                               const float* __restrict__ g1,
                                               const float* __restrict__ b1,
                                               float* __restrict__ ws) {
    __shared__ float4 w1s[C_IN * G4_HID];   // 3456 f
    __shared__ float M1s[576];
    __shared__ float MU1s[24];
    __shared__ float scf[C_HID], shf[C_HID];
    int t = threadIdx.x;
    for (int e = t; e < C_IN * G4_HID; e += 256) w1s[e] = ((const float4*)w1)[e];
    for (int e = t; e < 576; e += 256) M1s[e] = ws[M1_O + e];
    if (t < 24) MU1s[t] = ws[MU1_O + t];
    __syncthreads();
    // in-block fin1 (per-block recompute is ~1k cyc; M1s reads are same-address broadcast)
    if (t < C_HID) {
        const float* w1f = (const float*)w1s;
        float wc[C_IN];
#pragma unroll
        for (int k = 0; k < C_IN; k++) wc[k] = w1f[k * C_HID + t];
        const float invN = 1.f / (float)N_PTS;
        float mean = 0.f;
#pragma unroll
        for (int k = 0; k < C_IN; k++) mean += MU1s[k] * wc[k];
        mean *= invN;
        float e2 = 0.f;
        for (int i = 0; i < C_IN; i++) {
            float s = 0.f;
#pragma unroll
            for (int j = 0; j < C_IN; j++) s += M1s[i * 24 + j] * wc[j];
            e2 += wc[i] * s;
        }
        e2 *= invN;
        float var = e2 - mean * mean;
        float s1 = g1[t] * rsqrtf(var + EPSV);
        scf[t] = s1;
        shf[t] = b1[t] - mean * s1;
    }
    __syncthreads();
    const float4* sc4 = (const float4*)scf;
    const float4* sh4 = (const float4*)shf;
    uint4* x1u = (uint4*)ws;
    const int T = N_PTS * G8_HID;
    for (int tau = blockIdx.x * 256 + t; tau < T; tau += gridDim.x * 256) {
        int p = tau / G8_HID;
        int g = tau % G8_HID;
        const float4* fr = (const float4*)(feats + (size_t)p * C_IN);
        float4 a0 = f4z(), a1 = f4z();
#pragma unroll
        for (int q = 0; q < 6; q++) {
            float4 fq = fr[q];
            a0 = f4_fma_s(fq.x, w1s[(4 * q + 0) * G4_HID + 2 * g], a0);
            a1 = f4_fma_s(fq.x, w1s[(4 * q + 0) * G4_HID + 2 * g + 1], a1);
            a0 = f4_fma_s(fq.y, w1s[(4 * q + 1) * G4_HID + 2 * g], a0);
            a1 = f4_fma_s(fq.y, w1s[(4 * q + 1) * G4_HID + 2 * g + 1], a1);
            a0 = f4_fma_s(fq.z, w1s[(4 * q + 2) * G4_HID + 2 * g], a0);
            a1 = f4_fma_s(fq.z, w1s[(4 * q + 2) * G4_HID + 2 * g + 1], a1);
            a0 = f4_fma_s(fq.w, w1s[(4 * q + 3) * G4_HID + 2 * g], a0);
            a1 = f4_fma_s(fq.w, w1s[(4 * q + 3) * G4_HID + 2 * g + 1], a1);
        }
        a0 = f4_clamp6(f4_fma4(a0, sc4[2 * g], sh4[2 * g]));
        a1 = f4_clamp6(f4_fma4(a1, sc4[2 * g + 1], sh4[2 * g + 1]));
        uint4 o;
        o.x = pack2(a0.x, a0.y); o.y = pack2(a0.z, a0.w);
        o.z = pack2(a1.x, a1.y); o.w = pack2(a1.z, a1.w);
        x1u[tau] = o;
    }
}

// ---- K3: channelwise 3x3 conv (fp16 gather, 8ch/lane, LDS weights) + BN2 stats
// weights in LDS (not regs): round-3's 18xfloat4 reg preload cost VGPR 80 / occ 26%
__global__ __launch_bounds__(256, 6) void k_conv(const float* __restrict__ w2,
                                                 const int* __restrict__ in_idx,
                                                 float* __restrict__ ws) {
    __shared__ float4 w2s[KSZ * G4_HID];    // 5184 B
    __shared__ float lsum[C_HID], lsq[C_HID];
    int t = threadIdx.x;
    for (int e = t; e < KSZ * G4_HID; e += 256) w2s[e] = ((const float4*)w2)[e];
    if (t < C_HID) { lsum[t] = 0.f; lsq[t] = 0.f; }
    __syncthreads();
    const uint4* x1u = (const uint4*)ws;
    uint4* x2u = (uint4*)((char*)ws + X2H_B);
    bool active = t < 252;
    int pt = t / G8_HID, g = t % G8_HID;   // 14 points x 18 lane-groups
    float4 rsA = f4z(), rsB = f4z(), rqA = f4z(), rqB = f4z();
    int nChunks = (N_PTS + 13) / 14;
    for (int ch = blockIdx.x; ch < nChunks; ch += gridDim.x) {
        int p = ch * 14 + pt;
        if (active && p < N_PTS) {
            int idx[KSZ];
#pragma unroll
            for (int k = 0; k < KSZ; k++) idx[k] = in_idx[k * N_PTS + p];
            float4 aA = f4z(), aB = f4z();
#pragma unroll
            for (int k = 0; k < KSZ; k++) {
                uint4 v = x1u[(size_t)idx[k] * G8_HID + g];  // idx==N -> zero sentinel
                float2 f0 = uph(v.x), f1 = uph(v.y), f2 = uph(v.z), f3 = uph(v.w);
                aA = f4_fma4(w2s[k * G4_HID + 2 * g], make_float4(f0.x, f0.y, f1.x, f1.y), aA);
                aB = f4_fma4(w2s[k * G4_HID + 2 * g + 1], make_float4(f2.x, f2.y, f3.x, f3.y), aB);
            }
            uint4 o;
            o.x = pack2(aA.x, aA.y); o.y = pack2(aA.z, aA.w);
            o.z = pack2(aB.x, aB.y); o.w = pack2(aB.z, aB.w);
            x2u[(size_t)p * G8_HID + g] = o;
            rsA = f4_add(rsA, aA); rsB = f4_add(rsB, aB);
            rqA = f4_fma4(aA, aA, rqA); rqB = f4_fma4(aB, aB, rqB);
        }
    }
    if (active) {
        int c0 = 8 * g;
        atomicAdd(&lsum[c0 + 0], rsA.x); atomicAdd(&lsum[c0 + 1], rsA.y);
        atomicAdd(&lsum[c0 + 2], rsA.z); atomicAdd(&lsum[c0 + 3], rsA.w);
        atomicAdd(&lsum[c0 + 4], rsB.x); atomicAdd(&lsum[c0 + 5], rsB.y);
        atomicAdd(&lsum[c0 + 6], rsB.z); atomicAdd(&lsum[c0 + 7], rsB.w);
        atomicAdd(&lsq[c0 + 0], rqA.x);  atomicAdd(&lsq[c0 + 1], rqA.y);
        atomicAdd(&lsq[c0 + 2], rqA.z);  atomicAdd(&lsq[c0 + 3], rqA.w);
        atomicAdd(&lsq[c0 + 4], rqB.x);  atomicAdd(&lsq[c0 + 5], rqB.y);
        atomicAdd(&lsq[c0 + 6], rqB.z);  atomicAdd(&lsq[c0 + 7], rqB.w);
    }
    __syncthreads();
    if (t < C_HID) {
        atomicAdd(&ws[SUM2_O + t], lsum[t]);
        atomicAdd(&ws[SQ2_O + t], lsq[t]);
    }
}

// ---- K4: GEMM2 with in-block BN2 finalize (bn2+relu6 on the fly) -> y3 + BN3 stats
#define TP 64
__global__ __launch_bounds__(256) void k_gemm2(const float* __restrict__ w3,
                                               const float* __restrict__ g2,
                                               const float* __restrict__ b2,
                                               float* __restrict__ ws) {
    __shared__ float xs[TP * 145];
    __shared__ float w3s[C_HID * C_OUT];
    __shared__ float sc2s[C_HID], sh2s[C_HID];
    __shared__ float ssum[C_OUT], ssq[C_OUT];
    int t = threadIdx.x;
    for (int e = t; e < C_HID * C_OUT / 4; e += 256)
        ((float4*)w3s)[e] = ((const float4*)w3)[e];
    if (t < C_HID) {
        const float invN = 1.f / (float)N_PTS;
        float mean = ws[SUM2_O + t] * invN;
        float var = ws[SQ2_O + t] * invN - mean * mean;
        float s = g2[t] * rsqrtf(var + EPSV);
        sc2s[t] = s;
        sh2s[t] = b2[t] - mean * s;
    }
    if (t < C_OUT) { ssum[t] = 0.f; ssq[t] = 0.f; }
    __syncthreads();
    const uint4* x2u = (const uint4*)((char*)ws + X2H_B);
    int p0 = blockIdx.x * TP;
    for (int e = t; e < TP * G8_HID; e += 256) {
        int row = e / G8_HID, col = e % G8_HID;
        int p = p0 + row;
        int c0 = 8 * col;
        float v[8];
        if (p < N_PTS) {
            uint4 u = x2u[(size_t)p * G8_HID + col];
            float2 f0 = uph(u.x), f1 = uph(u.y), f2 = uph(u.z), f3 = uph(u.w);
            v[0] = f0.x; v[1] = f0.y; v[2] = f1.x; v[3] = f1.y;
            v[4] = f2.x; v[5] = f2.y; v[6] = f3.x; v[7] = f3.y;
#pragma unroll
            for (int i = 0; i < 8; i++)
                v[i] = fminf(fmaxf(fmaf(v[i], sc2s[c0 + i], sh2s[c0 + i]), 0.f), 6.f);
        } else {
#pragma unroll
            for (int i = 0; i < 8; i++) v[i] = 0.f;
        }
#pragma unroll
        for (int i = 0; i < 8; i++) xs[row * 145 + c0 + i] = v[i];
    }
    __syncthreads();
    int pl = t & 63, cg = t >> 6;
    int c0 = 6 * cg;
    float acc[6] = {0.f, 0.f, 0.f, 0.f, 0.f, 0.f};
    const float* xr = xs + pl * 145;
#pragma unroll 4
    for (int h = 0; h < C_HID; h++) {
        float x = xr[h];
#pragma unroll
        for (int j = 0; j < 6; j++) acc[j] = fmaf(x, w3s[h * C_OUT + c0 + j], acc[j]);
    }
    int p = p0 + pl;
    bool valid = p < N_PTS;
    float* y3 = ws + Y3F_O;
    if (valid) {
#pragma unroll
        for (int j = 0; j < 6; j++) y3[(size_t)p * C_OUT + c0 + j] = acc[j];
    }
    float s[6], q[6];
#pragma unroll
    for (int j = 0; j < 6; j++) {
        s[j] = valid ? acc[j] : 0.f;
        q[j] = s[j] * s[j];
    }
#pragma unroll
    for (int off = 32; off > 0; off >>= 1) {
#pragma unroll
        for (int j = 0; j < 6; j++) {
            s[j] += __shfl_down(s[j], off);
            q[j] += __shfl_down(q[j], off);
        }
    }
    if (pl == 0) {
#pragma unroll
        for (int j = 0; j < 6; j++) {
            atomicAdd(&ssum[c0 + j], s[j]);
            atomicAdd(&ssq[c0 + j], q[j]);
        }
    }
    __syncthreads();
    if (t < C_OUT) {
        atomicAdd(&ws[SUM3_O + t], ssum[t]);
        atomicAdd(&ws[SQ3_O + t], ssq[t]);
    }
}

// ---- K5: out = bn3(y3) + feats, with in-block BN3 finalize
__global__ __launch_bounds__(256) void k_out(const float* __restrict__ feats,
                                             const float* __restrict__ g3,
                                             const float* __restrict__ b3,
                                             const float* __restrict__ ws,
                                             float* __restrict__ out) {
    __shared__ float scs[C_OUT], shs[C_OUT];
    int t = threadIdx.x;
    if (t < C_OUT) {
        const float invN = 1.f / (float)N_PTS;
        float mean = ws[SUM3_O + t] * invN;
        float var = ws[SQ3_O + t] * invN - mean * mean;
        float s = g3[t] * rsqrtf(var + EPSV);
        scs[t] = s;
        shs[t] = b3[t] - mean * s;
    }
    __syncthreads();
    int t4 = blockIdx.x * 256 + t;
    const int T = N_PTS * G4_OUT;
    if (t4 >= T) return;
    int g = t4 % G4_OUT;
    float4 y = ((const float4*)(ws + Y3F_O))[t4];
    float4 s = ((const float4*)scs)[g];
    float4 b = ((const float4*)shs)[g];
    float4 f = ((const float4*)feats)[t4];
    ((float4*)out)[t4] = f4_add(f4_fma4(y, s, b), f);
}

extern "C" void kernel_launch(void* const* d_in, const int* in_sizes, int n_in,
                              void* d_out, int out_size, void* d_ws, size_t ws_size,
                              hipStream_t stream) {
    const float* feats = (const float*)d_in[0];
    const float* w1 = (const float*)d_in[1];
    const float* g1 = (const float*)d_in[2];
    const float* b1 = (const float*)d_in[3];
    const float* w2 = (const float*)d_in[4];
    const float* g2 = (const float*)d_in[5];
    const float* b2 = (const float*)d_in[6];
    const float* w3 = (const float*)d_in[7];
    const float* g3 = (const float*)d_in[8];
    const float* b3 = (const float*)d_in[9];
    const int* in_idx = (const int*)d_in[10];
    float* ws = (float*)d_ws;
    float* out = (float*)d_out;

    // zero stat accumulators (4 KB) + fp16 sentinel row (288 B) via memset nodes
    hipMemsetAsync((char*)d_ws + ST_B, 0, 4096, stream);
    hipMemsetAsync((char*)d_ws + SENT_B, 0, 288, stream);

    hipLaunchKernelGGL(k_moments, dim3(256), dim3(256), 0, stream, feats, ws);
    hipLaunchKernelGGL(k_gemm1, dim3(512), dim3(256), 0, stream, feats, w1, g1, b1, ws);
    hipLaunchKernelGGL(k_conv, dim3(2048), dim3(256), 0, stream, w2, in_idx, ws);
    hipLaunchKernelGGL(k_gemm2, dim3((N_PTS + TP - 1) / TP), dim3(256), 0, stream,
                       w3, g2, b2, ws);
    hipLaunchKernelGGL(k_out, dim3((N_PTS * G4_OUT + 255) / 256), dim3(256), 0, stream,
                       feats, g3, b3, ws, out);
}